// Round 4
// baseline (535.654 us; speedup 1.0000x reference)
//
#include <hip/hip_runtime.h>
#include <cstdint>
#include <cstddef>

#define B_ROWS 8192
#define OUT_N  1024
#define EXC_IN 4096
#define INH_IN 2048
#define K_EXC  32
#define K_INH  16
#define TILE_N 2

// ---------------------------------------------------------------------------
// Top-K: one wave per row, register-resident keys, shuffle-only reduction.
// Key = (monotone_u32(float) << 12) | (4095 - idx)  -> tie = lowest idx wins.
// ---------------------------------------------------------------------------
template<int COLS, int K>
__device__ __forceinline__ void topk_row(const float* __restrict__ src,
                                         float2* __restrict__ orow, int lane)
{
    constexpr int E4 = COLS / 256;          // float4 iters per lane
    unsigned long long keys[E4 * 4];
#pragma unroll
    for (int i = 0; i < E4; ++i) {
        const float4 v = ((const float4*)src)[i * 64 + lane];
        const float vv[4] = {v.x, v.y, v.z, v.w};
#pragma unroll
        for (int q = 0; q < 4; ++q) {
            const int idx = (i * 64 + lane) * 4 + q;
            const unsigned int u = __float_as_uint(vv[q]);
            const unsigned int m = (u >> 31) ? ~u : (u | 0x80000000u);
            keys[i * 4 + q] = ((unsigned long long)m << 12)
                            | (unsigned long long)(4095 - idx);
        }
    }

    unsigned long long win = 0xFFFFFFFFFFFFFFFFull;   // matches nothing
#pragma unroll 1
    for (int r = 0; r < K; ++r) {
        unsigned long long best = 0ull;
#pragma unroll
        for (int i = 0; i < E4 * 4; ++i) {
            const unsigned long long k2 = (keys[i] == win) ? 0ull : keys[i];
            keys[i] = k2;
            best = (k2 > best) ? k2 : best;
        }
#pragma unroll
        for (int m = 1; m < 64; m <<= 1) {
            const unsigned long long o = __shfl_xor(best, m, 64);
            best = (o > best) ? o : best;
        }
        win = best;
        if (lane == 0) {
            const unsigned int idx = 4095u - (unsigned int)(win & 0xFFFull);
            const unsigned int mm  = (unsigned int)(win >> 12);
            const unsigned int u   = (mm & 0x80000000u) ? (mm & 0x7FFFFFFFu) : ~mm;
            const float v = __uint_as_float(u);
            orow[r] = make_float2(expf(v), __uint_as_float(idx));
        }
    }
}

__global__ __launch_bounds__(256, 1) void topk_both_kernel(
    const float* __restrict__ pwe, const float* __restrict__ pwi,
    float2* __restrict__ wexc, float2* __restrict__ winh)
{
    const int wid  = (blockIdx.x * 256 + threadIdx.x) >> 6;   // global wave id
    const int lane = threadIdx.x & 63;
    if (wid < OUT_N) {
        topk_row<EXC_IN, K_EXC>(pwe + (size_t)wid * EXC_IN,
                                wexc + (size_t)wid * K_EXC, lane);
    } else {
        const int r = wid - OUT_N;                            // 0..1023
        topk_row<INH_IN, K_INH>(pwi + (size_t)r * INH_IN,
                                winh + (size_t)r * K_INH, lane);
    }
}

// ---------------------------------------------------------------------------
// Main fused kernel, TILE_N=2. LDS layout sx[c][n] (n fast, 2 rows) -> each
// gather is ONE ds_read_b64 covering both batch rows. 32 KB LDS/block ->
// ~5 blocks/CU (20 waves) for latency hiding; staging transpose is a single
// xor-shuffle exchange between lane pairs, writes contiguous b128.
// ---------------------------------------------------------------------------
__global__ __launch_bounds__(256, 5) void dendritic_main_kernel(
    const float*  __restrict__ x,
    const float*  __restrict__ inh,
    const float4* __restrict__ branch,   // [B][1024] float4
    const float2* __restrict__ wexc,     // [1024][32] (val, idx-bits)
    const float2* __restrict__ winh,     // [1024][16]
    const float4* __restrict__ wblock,   // [1024]
    const float*  __restrict__ presig,   // [1024]
    const float*  __restrict__ logalpha, // [1024]
    float*        __restrict__ out)      // [B][1024]
{
    __shared__ float sx[EXC_IN * TILE_N];   // 32 KB, [c][n] n-fast

    const int tid = threadIdx.x;
    const int n0  = blockIdx.x * TILE_N;
    const int jq  = tid & 1;        // row within lane pair
    const int c4b = tid >> 1;       // column-quad base (0..127 per iter chunk)

    // ---- stage x tile, transposed (pairwise shuffle exchange) ----
    // lane p0 holds A = x[n0][c0..c3], p1 holds B = x[n0+1][c0..c3].
    // p0 writes (A.x,B.x,A.y,B.y) at f4-index 2*c4; p1 writes (A.z,B.z,A.w,B.w)
    // at 2*c4+1  ==> sx[c*2+n] layout, contiguous b128 writes.
#pragma unroll
    for (int it = 0; it < (EXC_IN * TILE_N / 4) / 256; ++it) {   // 8
        const int c4 = c4b + it * 128;
        const float4 v = ((const float4*)(x + (size_t)(n0 + jq) * EXC_IN))[c4];
        const float s0 = jq ? v.x : v.z;
        const float s1 = jq ? v.y : v.w;
        const float r0 = __shfl_xor(s0, 1, 64);
        const float r1 = __shfl_xor(s1, 1, 64);
        const float4 wv = jq ? make_float4(r0, v.z, r1, v.w)
                             : make_float4(v.x, r0, v.y, r1);
        ((float4*)sx)[c4 * 2 + jq] = wv;
    }
    __syncthreads();

    // ---- excitation gather (b64: both batch rows per read) ----
    float acc_e[4][TILE_N];
#pragma unroll
    for (int j = 0; j < 4; ++j)
#pragma unroll
        for (int n = 0; n < TILE_N; ++n) acc_e[j][n] = 0.f;

#pragma unroll
    for (int j = 0; j < 4; ++j) {
        const int o = tid + j * 256;
        const float2* wr = wexc + (size_t)o * K_EXC;
#pragma unroll 8
        for (int k = 0; k < K_EXC; ++k) {
            const float2 wv = wr[k];
            const int c = (int)__float_as_uint(wv.y);
            const float2 xv = ((const float2*)sx)[c];
            acc_e[j][0] = fmaf(xv.x, wv.x, acc_e[j][0]);
            acc_e[j][1] = fmaf(xv.y, wv.x, acc_e[j][1]);
        }
    }
    __syncthreads();

    // ---- stage inh tile, transposed ----
#pragma unroll
    for (int it = 0; it < (INH_IN * TILE_N / 4) / 256; ++it) {   // 4
        const int c4 = c4b + it * 128;
        const float4 v = ((const float4*)(inh + (size_t)(n0 + jq) * INH_IN))[c4];
        const float s0 = jq ? v.x : v.z;
        const float s1 = jq ? v.y : v.w;
        const float r0 = __shfl_xor(s0, 1, 64);
        const float r1 = __shfl_xor(s1, 1, 64);
        const float4 wv = jq ? make_float4(r0, v.z, r1, v.w)
                             : make_float4(v.x, r0, v.y, r1);
        ((float4*)sx)[c4 * 2 + jq] = wv;
    }
    __syncthreads();

    // ---- inhibition gather (b64) ----
    float acc_i[4][TILE_N];
#pragma unroll
    for (int j = 0; j < 4; ++j)
#pragma unroll
        for (int n = 0; n < TILE_N; ++n) acc_i[j][n] = 0.f;

#pragma unroll
    for (int j = 0; j < 4; ++j) {
        const int o = tid + j * 256;
        const float2* wr = winh + (size_t)o * K_INH;
#pragma unroll 8
        for (int k = 0; k < K_INH; ++k) {
            const float2 wv = wr[k];
            const int c = (int)__float_as_uint(wv.y);
            const float2 xv = ((const float2*)sx)[c];
            acc_i[j][0] = fmaf(xv.x, wv.x, acc_i[j][0]);
            acc_i[j][1] = fmaf(xv.y, wv.x, acc_i[j][1]);
        }
    }

    // ---- branch contraction + voltage + reactivation ----
#pragma unroll
    for (int j = 0; j < 4; ++j) {
        const int o = tid + j * 256;
        const float4 wb = wblock[o];
        const float cond  = wb.x + wb.y + wb.z + wb.w;
        const float Vth   = 1.f / (1.f + expf(-presig[o]));
        const float alpha = expf(logalpha[o]);
#pragma unroll
        for (int n = 0; n < TILE_N; ++n) {
            const float4 br = branch[(size_t)(n0 + n) * OUT_N + o];
            const float cur = br.x * wb.x + br.y * wb.y + br.z * wb.z + br.w * wb.w;
            const float e  = acc_e[j][n];
            const float ii = acc_i[j][n];
            const float num = e + cur;
            const float den = e + 1.f + cond + ii;
            const float v   = num / den;
            const float d   = v - Vth;
            const float r   = alpha * d * d;
            out[(size_t)(n0 + n) * OUT_N + o] = (d < 0.f) ? 0.f : r;
        }
    }
}

// ---------------------------------------------------------------------------
extern "C" void kernel_launch(void* const* d_in, const int* in_sizes, int n_in,
                              void* d_out, int out_size, void* d_ws, size_t ws_size,
                              hipStream_t stream)
{
    const float* x      = (const float*)d_in[0];
    const float* inh    = (const float*)d_in[1];
    const float* branch = (const float*)d_in[2];
    const float* pwe    = (const float*)d_in[3];
    const float* pwi    = (const float*)d_in[4];
    const float* wb     = (const float*)d_in[5];
    const float* ps     = (const float*)d_in[6];
    const float* la     = (const float*)d_in[7];
    float* out = (float*)d_out;

    float2* wexc = (float2*)d_ws;
    float2* winh = (float2*)((char*)d_ws + (size_t)OUT_N * K_EXC * sizeof(float2));

    // 1024 exc waves + 1024 inh waves, 4 waves/block -> 512 blocks
    topk_both_kernel<<<(2 * OUT_N) / 4, 256, 0, stream>>>(pwe, pwi, wexc, winh);

    dendritic_main_kernel<<<B_ROWS / TILE_N, 256, 0, stream>>>(
        x, inh, (const float4*)branch, wexc, winh,
        (const float4*)wb, ps, la, out);
}